// Round 19
// baseline (139.561 us; speedup 1.0000x reference)
//
#include <hip/hip_runtime.h>
#include <hip/hip_bf16.h>

// Problem: B=128, M=256, T=512, N=512
// D[k][n] = sum_t We2T[k][t]*X[t][n] per b; e[b,n] = sum_k tanh(D+g[b,k])*v[k];
// attn = softmax_n(e).  k split in 2 block-halves (kblk); partials summed in
// softmax.
// R19 = R15 (best measured) with __launch_bounds__(256,4): the declared
// 3-waves/EU bound was itself the occupancy cap (VGPR 76, LDS 8KB allow 4).

typedef _Float16 half8 __attribute__((ext_vector_type(8)));
typedef float floatx4 __attribute__((ext_vector_type(4)));

__device__ __forceinline__ float fast_tanh(float x) {
    float cx = fminf(15.0f, fmaxf(-15.0f, x));
    float e = __expf(2.0f * cx);
    return (e - 1.0f) * __fdividef(1.0f, e + 1.0f);
}

// ---------------- K0: Af slabs (A = We2^T f16, frag-linear) ----------------
// slab ts (32 t), chunk c = k-16-group (0..31), lane l: holds
// A[k=c*16+(l&15)][t=ts*32+(l>>4)*8+j], j=0..7.  Elem ofs: ts*16384+c*512+l*8.
__global__ __launch_bounds__(256) void k_prep_a(const float* __restrict__ We2,
                                                _Float16* __restrict__ Af) {
    __shared__ float w2[32][512];
    const int ts = blockIdx.x;
    for (int idx = threadIdx.x; idx < 32 * 512; idx += 256) {
        int tl = idx >> 9, k = idx & 511;
        w2[tl][k] = We2[(ts * 32 + tl) * 512 + k];
    }
    __syncthreads();
    for (int item = threadIdx.x; item < 32 * 64; item += 256) {
        int c = item >> 6, l = item & 63;
        int k  = c * 16 + (l & 15);
        int tl = (l >> 4) * 8;
        half8 h;
#pragma unroll
        for (int j = 0; j < 8; ++j) h[j] = (_Float16)w2[tl + j][k];
        *(half8*)&Af[(((size_t)ts * 32 + c) * 64 + l) * 8] = h;
    }
}

// ---------------- K1: g[b][k] = hc@We1 + be1 + be2 ----------------
__global__ __launch_bounds__(256) void k_hs(const float* __restrict__ hidden,
                                            const float* __restrict__ cell,
                                            const float* __restrict__ We1,
                                            const float* __restrict__ be1,
                                            const float* __restrict__ be2,
                                            float* __restrict__ g) {
    __shared__ __align__(16) float hcl[8][512];
    __shared__ float red[4][8][64];
    const int b0 = (blockIdx.x >> 3) << 3;
    const int k0 = (blockIdx.x & 7) << 6;
    for (int idx = threadIdx.x; idx < 8 * 512; idx += 256) {
        int bi = idx >> 9, j = idx & 511;
        hcl[bi][j] = (j < 256) ? hidden[(b0 + bi) * 256 + j]
                               : cell[(b0 + bi) * 256 + j - 256];
    }
    __syncthreads();
    const int kl = threadIdx.x & 63;
    const int jc = threadIdx.x >> 6;
    const int k  = k0 + kl;
    float acc[8] = {};
    for (int j = jc * 128; j < jc * 128 + 128; j += 4) {
        float w0 = We1[(j + 0) * 512 + k];
        float w1 = We1[(j + 1) * 512 + k];
        float w2 = We1[(j + 2) * 512 + k];
        float w3 = We1[(j + 3) * 512 + k];
#pragma unroll
        for (int bi = 0; bi < 8; ++bi) {
            float4 h = *(const float4*)&hcl[bi][j];
            acc[bi] += h.x * w0 + h.y * w1 + h.z * w2 + h.w * w3;
        }
    }
#pragma unroll
    for (int bi = 0; bi < 8; ++bi) red[jc][bi][kl] = acc[bi];
    __syncthreads();
    for (int idx = threadIdx.x; idx < 512; idx += 256) {
        int bi = idx >> 6, kk = idx & 63;
        float s = red[0][bi][kk] + red[1][bi][kk] + red[2][bi][kk] + red[3][bi][kk];
        int kg = k0 + kk;
        g[(b0 + bi) * 512 + kg] = s + be1[kg] + be2[kg];
    }
}

// ---------------- K2: fused GEMM, lean-LDS, BK=32, A reg-dbuf ----------------
// grid 2048 = 128b x 8nt(64n) x 2kblk(256k), XCD chunk-swizzle.  256 thr =
// 4 waves; wave wv owns k [kblk*256+wv*64,+64) x 64n -> acc 4x4 = 16 MFMA /
// step, 16 steps.  A: global b128 from L2-hot Af, register double-buffer one
// step ahead.  X: f16 LDS dbuf 2x4KB t-contiguous, XOR-slot swizzle, b128
// frag reads; X loads 3-set-deep in regs.
__global__ __launch_bounds__(256, 4) void k_main(const float* __restrict__ X,
                                                 const _Float16* __restrict__ Af,
                                                 const float* __restrict__ g,
                                                 const float* __restrict__ vvec,
                                                 float* __restrict__ Ep) {
    __shared__ __align__(16) _Float16 Xb[2][2048];   // 2 x 4 KB
    const int tid  = threadIdx.x;
    const int lane = tid & 63;
    const int wv   = tid >> 6;        // 0..3
    const int l16  = lane & 15;
    const int lhi  = lane >> 4;       // 0..3
    const int logical = (blockIdx.x & 7) * 256 + (blockIdx.x >> 3);
    const int kblk = logical & 1;
    const int nt   = (logical >> 1) & 7;
    const int b    = logical >> 4;
    const int n0   = nt << 6;

    const float* Xg = X + (size_t)b * 262144 + n0;
    const _Float16* Ag = Af + (size_t)(kblk * 16 + wv * 4) * 512 + (size_t)lane * 8;

    // X staging: thread (xn = tid&63 -> n, xo = tid>>6 -> t-octet).
    const int xn = tid & 63;
    const int xo = tid >> 6;
    const float* Xt = Xg + (size_t)(xo * 8) * 512 + xn;   // + s*16384 + j*512
    const int wslot = xn * 32 + ((xo ^ (xn & 3) ^ ((xn >> 2) & 3)) << 3);
    int roff[4];
#pragma unroll
    for (int nf = 0; nf < 4; ++nf) {
        int n = nf * 16 + l16;
        roff[nf] = n * 32 + ((lhi ^ (n & 3) ^ ((n >> 2) & 3)) << 3);
    }

    float xs0[8], xs1[8], xs2[8];     // X(m) lives in set m%3
#define XLOAD(s_, arr_)                                                        \
    do { _Pragma("unroll")                                                     \
         for (int j = 0; j < 8; ++j)                                           \
             arr_[j] = Xt[(size_t)(s_) * 16384 + (size_t)j * 512];             \
    } while (0)
#define XSTORE(s_, arr_)                                                       \
    do { half8 h;                                                              \
         _Pragma("unroll")                                                     \
         for (int j = 0; j < 8; ++j) h[j] = (_Float16)arr_[j];                 \
         *(half8*)&Xb[(s_) & 1][wslot] = h;                                    \
    } while (0)
#define ALOAD(s_, arr_)                                                        \
    do { _Pragma("unroll")                                                     \
         for (int kf = 0; kf < 4; ++kf)                                        \
             arr_[kf] = *(const half8*)(Ag + (size_t)(s_) * 16384 +            \
                                        (size_t)kf * 512);                     \
    } while (0)

    half8 afA[4], afB[4];

    // ---- prologue: X(0..2) + A(0) in flight; X(0) -> Xb[0]
    XLOAD(0, xs0);
    XLOAD(1, xs1);
    XLOAD(2, xs2);
    ALOAD(0, afA);
    XSTORE(0, xs0);                   // positional wait covers X(0) only
    asm volatile("s_waitcnt lgkmcnt(0)" ::: "memory");
    __builtin_amdgcn_sched_barrier(0);
    __builtin_amdgcn_s_barrier();
    __builtin_amdgcn_sched_barrier(0);

    floatx4 acc[4][4];
#pragma unroll
    for (int a = 0; a < 4; ++a)
#pragma unroll
        for (int c = 0; c < 4; ++c) acc[a][c] = (floatx4){0.f, 0.f, 0.f, 0.f};

#pragma unroll
    for (int s = 0; s < 16; ++s) {
        const int cur = s & 1;
        // 1. issue A(s+1) into the spare named set (newest VMEM before X)
        if (s + 1 < 16) {
            if ((s & 1) == 0) ALOAD(s + 1, afB);
            else              ALOAD(s + 1, afA);
        }
        // 2. issue X(s+3) into reg set (s%3)
        if (s + 3 < 16) {
            if ((s % 3) == 0)      XLOAD(s + 3, xs0);
            else if ((s % 3) == 1) XLOAD(s + 3, xs1);
            else                   XLOAD(s + 3, xs2);
        }
        __builtin_amdgcn_sched_barrier(0);   // pin issue block at step top
        // 3. X(s) fragments: 4 x ds_read_b128 (swizzled, even-spread)
        half8 bf[4];
#pragma unroll
        for (int nf = 0; nf < 4; ++nf)
            bf[nf] = *(const half8*)&Xb[cur][roff[nf]];
        // 4. cvt + write X(s+1) (regs landed 2 steps ago; counted wait leaves
        //    A(s+1)/X(s+3) in flight) into Xb[cur^1]
        if (s + 1 < 16) {
            if (((s + 1) % 3) == 0)      XSTORE(s + 1, xs0);
            else if (((s + 1) % 3) == 1) XSTORE(s + 1, xs1);
            else                         XSTORE(s + 1, xs2);
        }
        // 5. MFMA cluster with A(s) prefetched LAST step (no fresh latency)
        __builtin_amdgcn_s_setprio(1);
        if ((s & 1) == 0) {
#pragma unroll
            for (int kf = 0; kf < 4; ++kf)
#pragma unroll
                for (int nf = 0; nf < 4; ++nf)
                    acc[kf][nf] = __builtin_amdgcn_mfma_f32_16x16x32_f16(
                        afA[kf], bf[nf], acc[kf][nf], 0, 0, 0);
        } else {
#pragma unroll
            for (int kf = 0; kf < 4; ++kf)
#pragma unroll
                for (int nf = 0; nf < 4; ++nf)
                    acc[kf][nf] = __builtin_amdgcn_mfma_f32_16x16x32_f16(
                        afB[kf], bf[nf], acc[kf][nf], 0, 0, 0);
        }
        __builtin_amdgcn_s_setprio(0);
        // 6. LDS drain + barrier (no vmcnt: A/X prefetches stay in flight)
        asm volatile("s_waitcnt lgkmcnt(0)" ::: "memory");
        __builtin_amdgcn_sched_barrier(0);
        __builtin_amdgcn_s_barrier();
        __builtin_amdgcn_sched_barrier(0);
    }
#undef XLOAD
#undef XSTORE
#undef ALOAD

    // ---- fused epilogue: s[n] = sum_{k slice} tanh(acc+g)*v
    // D layout: row k = lhi*4+reg (within kf 16-group), col n = l16
    const float* gb = g + b * 512;
    float sacc[4] = {0.f, 0.f, 0.f, 0.f};
#pragma unroll
    for (int kf = 0; kf < 4; ++kf) {
        const int kb = kblk * 256 + wv * 64 + kf * 16 + lhi * 4;
        float g0 = gb[kb + 0], g1 = gb[kb + 1], g2 = gb[kb + 2], g3 = gb[kb + 3];
        float v0 = vvec[kb + 0], v1 = vvec[kb + 1], v2 = vvec[kb + 2], v3 = vvec[kb + 3];
#pragma unroll
        for (int nf = 0; nf < 4; ++nf) {
            sacc[nf] += fast_tanh(acc[kf][nf][0] + g0) * v0;
            sacc[nf] += fast_tanh(acc[kf][nf][1] + g1) * v1;
            sacc[nf] += fast_tanh(acc[kf][nf][2] + g2) * v2;
            sacc[nf] += fast_tanh(acc[kf][nf][3] + g3) * v3;
        }
    }
#pragma unroll
    for (int nf = 0; nf < 4; ++nf) {
        sacc[nf] += __shfl_xor(sacc[nf], 16);
        sacc[nf] += __shfl_xor(sacc[nf], 32);
    }
    __syncthreads();                 // loop done -> overlay on Xb
    float* ered = (float*)&Xb[0][0]; // [4 waves][64 n]
    if (lane < 16) {
#pragma unroll
        for (int nf = 0; nf < 4; ++nf) ered[wv * 64 + nf * 16 + l16] = sacc[nf];
    }
    __syncthreads();
    if (tid < 64) {
        float e = ered[tid] + ered[64 + tid] + ered[128 + tid] + ered[192 + tid];
        Ep[(size_t)kblk * 65536 + b * 512 + n0 + tid] = e;
    }
}

// ---------------- K3: softmax over n (512), summing 2 k-partials ------------
__global__ __launch_bounds__(256) void k_softmax(const float* __restrict__ Ep,
                                                 float* __restrict__ out) {
    __shared__ float rmax[4], rsum[4];
    const int b = blockIdx.x;
    const int tid = threadIdx.x;
    const float* E0 = Ep;
    const float* E1 = Ep + 65536;
    float e0 = E0[b * 512 + tid] + E1[b * 512 + tid];
    float e1 = E0[b * 512 + 256 + tid] + E1[b * 512 + 256 + tid];
    float m = fmaxf(e0, e1);
    for (int o = 32; o > 0; o >>= 1) m = fmaxf(m, __shfl_xor(m, o));
    if ((tid & 63) == 0) rmax[tid >> 6] = m;
    __syncthreads();
    m = fmaxf(fmaxf(rmax[0], rmax[1]), fmaxf(rmax[2], rmax[3]));
    float p0 = __expf(e0 - m), p1 = __expf(e1 - m);
    float ss = p0 + p1;
    for (int o = 32; o > 0; o >>= 1) ss += __shfl_xor(ss, o);
    if ((tid & 63) == 0) rsum[tid >> 6] = ss;
    __syncthreads();
    ss = rsum[0] + rsum[1] + rsum[2] + rsum[3];
    float inv = __fdividef(1.0f, ss);
    out[b * 512 + tid] = p0 * inv;
    out[b * 512 + 256 + tid] = p1 * inv;
}

extern "C" void kernel_launch(void* const* d_in, const int* in_sizes, int n_in,
                              void* d_out, int out_size, void* d_ws, size_t ws_size,
                              hipStream_t stream) {
    const float* hidden = (const float*)d_in[0];
    const float* cell   = (const float*)d_in[1];
    const float* X      = (const float*)d_in[2];
    const float* We1    = (const float*)d_in[3];
    const float* be1    = (const float*)d_in[4];
    const float* We2    = (const float*)d_in[5];
    const float* be2    = (const float*)d_in[6];
    const float* v      = (const float*)d_in[7];
    float* out = (float*)d_out;

    char* ws = (char*)d_ws;
    _Float16* Af = (_Float16*)ws;                        // 512*512*2   = 524288 B
    float* g     = (float*)(ws + 524288);                // 128*512*4   = 262144 B
    float* Ep    = (float*)(ws + 786432);                // 2*128*512*4 = 524288 B

    k_prep_a<<<16, 256, 0, stream>>>(We2, Af);
    k_hs<<<128, 256, 0, stream>>>(hidden, cell, We1, be1, be2, g);
    k_main<<<2048, 256, 0, stream>>>(X, Af, g, v, Ep);
    k_softmax<<<128, 256, 0, stream>>>(Ep, out);
}

// Round 20
// 76.867 us; speedup vs baseline: 1.8156x; 1.8156x over previous
//
#include <hip/hip_runtime.h>
#include <hip/hip_bf16.h>

// Problem: B=128, M=256, T=512, N=512
// D[k][n] = sum_t We2T[k][t]*X[t][n] per b; e[b,n] = sum_k tanh(D+g[b,k])*v[k];
// attn = softmax_n(e).  k split in 2 block-halves (kblk); partials summed in
// softmax.
// R20 = R15 verbatim (best measured: 76.8 us total).  R19's (256,4) bound
// caused scratch spills (WRITE_SIZE 0.5 MB -> 188 MB): (256,3) is load-bearing.

typedef _Float16 half8 __attribute__((ext_vector_type(8)));
typedef float floatx4 __attribute__((ext_vector_type(4)));

__device__ __forceinline__ float fast_tanh(float x) {
    float cx = fminf(15.0f, fmaxf(-15.0f, x));
    float e = __expf(2.0f * cx);
    return (e - 1.0f) * __fdividef(1.0f, e + 1.0f);
}

// ---------------- K0: Af slabs (A = We2^T f16, frag-linear) ----------------
// slab ts (32 t), chunk c = k-16-group (0..31), lane l: holds
// A[k=c*16+(l&15)][t=ts*32+(l>>4)*8+j], j=0..7.  Elem ofs: ts*16384+c*512+l*8.
__global__ __launch_bounds__(256) void k_prep_a(const float* __restrict__ We2,
                                                _Float16* __restrict__ Af) {
    __shared__ float w2[32][512];
    const int ts = blockIdx.x;
    for (int idx = threadIdx.x; idx < 32 * 512; idx += 256) {
        int tl = idx >> 9, k = idx & 511;
        w2[tl][k] = We2[(ts * 32 + tl) * 512 + k];
    }
    __syncthreads();
    for (int item = threadIdx.x; item < 32 * 64; item += 256) {
        int c = item >> 6, l = item & 63;
        int k  = c * 16 + (l & 15);
        int tl = (l >> 4) * 8;
        half8 h;
#pragma unroll
        for (int j = 0; j < 8; ++j) h[j] = (_Float16)w2[tl + j][k];
        *(half8*)&Af[(((size_t)ts * 32 + c) * 64 + l) * 8] = h;
    }
}

// ---------------- K1: g[b][k] = hc@We1 + be1 + be2 ----------------
__global__ __launch_bounds__(256) void k_hs(const float* __restrict__ hidden,
                                            const float* __restrict__ cell,
                                            const float* __restrict__ We1,
                                            const float* __restrict__ be1,
                                            const float* __restrict__ be2,
                                            float* __restrict__ g) {
    __shared__ __align__(16) float hcl[8][512];
    __shared__ float red[4][8][64];
    const int b0 = (blockIdx.x >> 3) << 3;
    const int k0 = (blockIdx.x & 7) << 6;
    for (int idx = threadIdx.x; idx < 8 * 512; idx += 256) {
        int bi = idx >> 9, j = idx & 511;
        hcl[bi][j] = (j < 256) ? hidden[(b0 + bi) * 256 + j]
                               : cell[(b0 + bi) * 256 + j - 256];
    }
    __syncthreads();
    const int kl = threadIdx.x & 63;
    const int jc = threadIdx.x >> 6;
    const int k  = k0 + kl;
    float acc[8] = {};
    for (int j = jc * 128; j < jc * 128 + 128; j += 4) {
        float w0 = We1[(j + 0) * 512 + k];
        float w1 = We1[(j + 1) * 512 + k];
        float w2 = We1[(j + 2) * 512 + k];
        float w3 = We1[(j + 3) * 512 + k];
#pragma unroll
        for (int bi = 0; bi < 8; ++bi) {
            float4 h = *(const float4*)&hcl[bi][j];
            acc[bi] += h.x * w0 + h.y * w1 + h.z * w2 + h.w * w3;
        }
    }
#pragma unroll
    for (int bi = 0; bi < 8; ++bi) red[jc][bi][kl] = acc[bi];
    __syncthreads();
    for (int idx = threadIdx.x; idx < 512; idx += 256) {
        int bi = idx >> 6, kk = idx & 63;
        float s = red[0][bi][kk] + red[1][bi][kk] + red[2][bi][kk] + red[3][bi][kk];
        int kg = k0 + kk;
        g[(b0 + bi) * 512 + kg] = s + be1[kg] + be2[kg];
    }
}

// ---------------- K2: fused GEMM, lean-LDS, BK=32, A reg-dbuf ----------------
// grid 2048 = 128b x 8nt(64n) x 2kblk(256k), XCD chunk-swizzle.  256 thr =
// 4 waves; wave wv owns k [kblk*256+wv*64,+64) x 64n -> acc 4x4 = 16 MFMA /
// step, 16 steps.  A: global b128 from L2-hot Af, register double-buffer one
// step ahead.  X: f16 LDS dbuf 2x4KB t-contiguous, XOR-slot swizzle, b128
// frag reads; X loads 3-set-deep in regs.
__global__ __launch_bounds__(256, 3) void k_main(const float* __restrict__ X,
                                                 const _Float16* __restrict__ Af,
                                                 const float* __restrict__ g,
                                                 const float* __restrict__ vvec,
                                                 float* __restrict__ Ep) {
    __shared__ __align__(16) _Float16 Xb[2][2048];   // 2 x 4 KB
    const int tid  = threadIdx.x;
    const int lane = tid & 63;
    const int wv   = tid >> 6;        // 0..3
    const int l16  = lane & 15;
    const int lhi  = lane >> 4;       // 0..3
    const int logical = (blockIdx.x & 7) * 256 + (blockIdx.x >> 3);
    const int kblk = logical & 1;
    const int nt   = (logical >> 1) & 7;
    const int b    = logical >> 4;
    const int n0   = nt << 6;

    const float* Xg = X + (size_t)b * 262144 + n0;
    const _Float16* Ag = Af + (size_t)(kblk * 16 + wv * 4) * 512 + (size_t)lane * 8;

    // X staging: thread (xn = tid&63 -> n, xo = tid>>6 -> t-octet).
    const int xn = tid & 63;
    const int xo = tid >> 6;
    const float* Xt = Xg + (size_t)(xo * 8) * 512 + xn;   // + s*16384 + j*512
    const int wslot = xn * 32 + ((xo ^ (xn & 3) ^ ((xn >> 2) & 3)) << 3);
    int roff[4];
#pragma unroll
    for (int nf = 0; nf < 4; ++nf) {
        int n = nf * 16 + l16;
        roff[nf] = n * 32 + ((lhi ^ (n & 3) ^ ((n >> 2) & 3)) << 3);
    }

    float xs0[8], xs1[8], xs2[8];     // X(m) lives in set m%3
#define XLOAD(s_, arr_)                                                        \
    do { _Pragma("unroll")                                                     \
         for (int j = 0; j < 8; ++j)                                           \
             arr_[j] = Xt[(size_t)(s_) * 16384 + (size_t)j * 512];             \
    } while (0)
#define XSTORE(s_, arr_)                                                       \
    do { half8 h;                                                              \
         _Pragma("unroll")                                                     \
         for (int j = 0; j < 8; ++j) h[j] = (_Float16)arr_[j];                 \
         *(half8*)&Xb[(s_) & 1][wslot] = h;                                    \
    } while (0)
#define ALOAD(s_, arr_)                                                        \
    do { _Pragma("unroll")                                                     \
         for (int kf = 0; kf < 4; ++kf)                                        \
             arr_[kf] = *(const half8*)(Ag + (size_t)(s_) * 16384 +            \
                                        (size_t)kf * 512);                     \
    } while (0)

    half8 afA[4], afB[4];

    // ---- prologue: X(0..2) + A(0) in flight; X(0) -> Xb[0]
    XLOAD(0, xs0);
    XLOAD(1, xs1);
    XLOAD(2, xs2);
    ALOAD(0, afA);
    XSTORE(0, xs0);                   // positional wait covers X(0) only
    asm volatile("s_waitcnt lgkmcnt(0)" ::: "memory");
    __builtin_amdgcn_sched_barrier(0);
    __builtin_amdgcn_s_barrier();
    __builtin_amdgcn_sched_barrier(0);

    floatx4 acc[4][4];
#pragma unroll
    for (int a = 0; a < 4; ++a)
#pragma unroll
        for (int c = 0; c < 4; ++c) acc[a][c] = (floatx4){0.f, 0.f, 0.f, 0.f};

#pragma unroll
    for (int s = 0; s < 16; ++s) {
        const int cur = s & 1;
        // 1. issue A(s+1) into the spare named set (newest VMEM before X)
        if (s + 1 < 16) {
            if ((s & 1) == 0) ALOAD(s + 1, afB);
            else              ALOAD(s + 1, afA);
        }
        // 2. issue X(s+3) into reg set (s%3)
        if (s + 3 < 16) {
            if ((s % 3) == 0)      XLOAD(s + 3, xs0);
            else if ((s % 3) == 1) XLOAD(s + 3, xs1);
            else                   XLOAD(s + 3, xs2);
        }
        __builtin_amdgcn_sched_barrier(0);   // pin issue block at step top
        // 3. X(s) fragments: 4 x ds_read_b128 (swizzled, even-spread)
        half8 bf[4];
#pragma unroll
        for (int nf = 0; nf < 4; ++nf)
            bf[nf] = *(const half8*)&Xb[cur][roff[nf]];
        // 4. cvt + write X(s+1) (regs landed 2 steps ago; counted wait leaves
        //    A(s+1)/X(s+3) in flight) into Xb[cur^1]
        if (s + 1 < 16) {
            if (((s + 1) % 3) == 0)      XSTORE(s + 1, xs0);
            else if (((s + 1) % 3) == 1) XSTORE(s + 1, xs1);
            else                         XSTORE(s + 1, xs2);
        }
        // 5. MFMA cluster with A(s) prefetched LAST step (no fresh latency)
        __builtin_amdgcn_s_setprio(1);
        if ((s & 1) == 0) {
#pragma unroll
            for (int kf = 0; kf < 4; ++kf)
#pragma unroll
                for (int nf = 0; nf < 4; ++nf)
                    acc[kf][nf] = __builtin_amdgcn_mfma_f32_16x16x32_f16(
                        afA[kf], bf[nf], acc[kf][nf], 0, 0, 0);
        } else {
#pragma unroll
            for (int kf = 0; kf < 4; ++kf)
#pragma unroll
                for (int nf = 0; nf < 4; ++nf)
                    acc[kf][nf] = __builtin_amdgcn_mfma_f32_16x16x32_f16(
                        afB[kf], bf[nf], acc[kf][nf], 0, 0, 0);
        }
        __builtin_amdgcn_s_setprio(0);
        // 6. LDS drain + barrier (no vmcnt: A/X prefetches stay in flight)
        asm volatile("s_waitcnt lgkmcnt(0)" ::: "memory");
        __builtin_amdgcn_sched_barrier(0);
        __builtin_amdgcn_s_barrier();
        __builtin_amdgcn_sched_barrier(0);
    }
#undef XLOAD
#undef XSTORE
#undef ALOAD

    // ---- fused epilogue: s[n] = sum_{k slice} tanh(acc+g)*v
    // D layout: row k = lhi*4+reg (within kf 16-group), col n = l16
    const float* gb = g + b * 512;
    float sacc[4] = {0.f, 0.f, 0.f, 0.f};
#pragma unroll
    for (int kf = 0; kf < 4; ++kf) {
        const int kb = kblk * 256 + wv * 64 + kf * 16 + lhi * 4;
        float g0 = gb[kb + 0], g1 = gb[kb + 1], g2 = gb[kb + 2], g3 = gb[kb + 3];
        float v0 = vvec[kb + 0], v1 = vvec[kb + 1], v2 = vvec[kb + 2], v3 = vvec[kb + 3];
#pragma unroll
        for (int nf = 0; nf < 4; ++nf) {
            sacc[nf] += fast_tanh(acc[kf][nf][0] + g0) * v0;
            sacc[nf] += fast_tanh(acc[kf][nf][1] + g1) * v1;
            sacc[nf] += fast_tanh(acc[kf][nf][2] + g2) * v2;
            sacc[nf] += fast_tanh(acc[kf][nf][3] + g3) * v3;
        }
    }
#pragma unroll
    for (int nf = 0; nf < 4; ++nf) {
        sacc[nf] += __shfl_xor(sacc[nf], 16);
        sacc[nf] += __shfl_xor(sacc[nf], 32);
    }
    __syncthreads();                 // loop done -> overlay on Xb
    float* ered = (float*)&Xb[0][0]; // [4 waves][64 n]
    if (lane < 16) {
#pragma unroll
        for (int nf = 0; nf < 4; ++nf) ered[wv * 64 + nf * 16 + l16] = sacc[nf];
    }
    __syncthreads();
    if (tid < 64) {
        float e = ered[tid] + ered[64 + tid] + ered[128 + tid] + ered[192 + tid];
        Ep[(size_t)kblk * 65536 + b * 512 + n0 + tid] = e;
    }
}

// ---------------- K3: softmax over n (512), summing 2 k-partials ------------
__global__ __launch_bounds__(256) void k_softmax(const float* __restrict__ Ep,
                                                 float* __restrict__ out) {
    __shared__ float rmax[4], rsum[4];
    const int b = blockIdx.x;
    const int tid = threadIdx.x;
    const float* E0 = Ep;
    const float* E1 = Ep + 65536;
    float e0 = E0[b * 512 + tid] + E1[b * 512 + tid];
    float e1 = E0[b * 512 + 256 + tid] + E1[b * 512 + 256 + tid];
    float m = fmaxf(e0, e1);
    for (int o = 32; o > 0; o >>= 1) m = fmaxf(m, __shfl_xor(m, o));
    if ((tid & 63) == 0) rmax[tid >> 6] = m;
    __syncthreads();
    m = fmaxf(fmaxf(rmax[0], rmax[1]), fmaxf(rmax[2], rmax[3]));
    float p0 = __expf(e0 - m), p1 = __expf(e1 - m);
    float ss = p0 + p1;
    for (int o = 32; o > 0; o >>= 1) ss += __shfl_xor(ss, o);
    if ((tid & 63) == 0) rsum[tid >> 6] = ss;
    __syncthreads();
    ss = rsum[0] + rsum[1] + rsum[2] + rsum[3];
    float inv = __fdividef(1.0f, ss);
    out[b * 512 + tid] = p0 * inv;
    out[b * 512 + 256 + tid] = p1 * inv;
}

extern "C" void kernel_launch(void* const* d_in, const int* in_sizes, int n_in,
                              void* d_out, int out_size, void* d_ws, size_t ws_size,
                              hipStream_t stream) {
    const float* hidden = (const float*)d_in[0];
    const float* cell   = (const float*)d_in[1];
    const float* X      = (const float*)d_in[2];
    const float* We1    = (const float*)d_in[3];
    const float* be1    = (const float*)d_in[4];
    const float* We2    = (const float*)d_in[5];
    const float* be2    = (const float*)d_in[6];
    const float* v      = (const float*)d_in[7];
    float* out = (float*)d_out;

    char* ws = (char*)d_ws;
    _Float16* Af = (_Float16*)ws;                        // 512*512*2   = 524288 B
    float* g     = (float*)(ws + 524288);                // 128*512*4   = 262144 B
    float* Ep    = (float*)(ws + 786432);                // 2*128*512*4 = 524288 B

    k_prep_a<<<16, 256, 0, stream>>>(We2, Af);
    k_hs<<<128, 256, 0, stream>>>(hidden, cell, We1, be1, be2, g);
    k_main<<<2048, 256, 0, stream>>>(X, Af, g, v, Ep);
    k_softmax<<<128, 256, 0, stream>>>(Ep, out);
}